// Round 16
// baseline (265.980 us; speedup 1.0000x reference)
//
#include <hip/hip_runtime.h>
#include <stdint.h>

#pragma clang fp contract(off)

#define NCLS   20
#define NA     5
#define NB     16
#define Hg     26
#define Wg     26
#define HWc    (Hg*Wg)            // 676
#define NBOX   (NA*HWc)           // 3380
#define NPAD   4096
#define NWRD   (NPAD/64)          // 64
#define NROW   3392               // 53*64, padded row count
#define SWRD   53                 // words covering 3380 boxes
#define RGRP   27                 // ceil(NROW/128): 128-row groups
#define PROBC  (NCLS+1)           // 21
#define PRE_TH 0.005f
#define NMS_TH 0.45f
#define ETOT   88192              // 32*53*52: worst-case entries per batch
#define SEGB(c) (32*(c)*((c)-1))  // segment base for chunk c (capacity c*64)

__constant__ float c_bias[10] = {1.08f,1.19f,3.42f,4.41f,6.63f,11.38f,9.42f,5.11f,16.62f,10.52f};

__device__ __forceinline__ unsigned long long rl64(unsigned long long v, int k) {
  unsigned int lo = (unsigned int)__builtin_amdgcn_readlane((int)(unsigned int)v, k);
  unsigned int hi = (unsigned int)__builtin_amdgcn_readlane((int)(unsigned int)(v >> 32), k);
  return ((unsigned long long)hi << 32) | lo;
}

// ---------------------------------------------------------------- decode ----
__global__ __launch_bounds__(256) void k_decode(const float* __restrict__ x,
                                                const float* __restrict__ im_info,
                                                float* __restrict__ out,
                                                float* __restrict__ scores) {
  int t = blockIdx.x * 256 + threadIdx.x;
  if (t >= NB * NBOX) return;
  int b  = t / NBOX;
  int n  = t - b * NBOX;
  int a  = n / HWc;
  int hw = n - a * HWc;
  int h  = hw / Wg;
  int w  = hw - h * Wg;

  const float* xb = x + (size_t)b * 125 * HWc;
  float tx = xb[(2*a  ) * HWc + hw];
  float ty = xb[(2*a+1) * HWc + hw];
  float tw = xb[(10+2*a) * HWc + hw];
  float th = xb[(11+2*a) * HWc + hw];
  float to = xb[(20+a  ) * HWc + hw];

  float sx  = 1.0f / (1.0f + expf(-tx));
  float sy  = 1.0f / (1.0f + expf(-ty));
  float obj = 1.0f / (1.0f + expf(-to));

  float cf[NCLS];
  float mx = -3.402823e38f;
#pragma unroll
  for (int c = 0; c < NCLS; ++c) {
    cf[c] = xb[(25 + c*NA + a) * HWc + hw];
    mx = fmaxf(mx, cf[c]);
  }
  float sum = 0.f;
#pragma unroll
  for (int c = 0; c < NCLS; ++c) { cf[c] = expf(cf[c] - mx); sum += cf[c]; }

  float* op = out + ((size_t)b * NBOX + n) * PROBC;
#pragma unroll
  for (int c = 0; c < NCLS; ++c) op[c] = cf[c] / sum * obj;
  op[NCLS] = 0.f;   // obj channel; scan kernel writes kept scores later

  // box decode — replicate reference op order exactly
  float Wf = (float)Wg, Hf = (float)Hg;
  float bx = ((float)w + sx) / Wf;
  float by = ((float)h + sy) / Hf;
  float bw = c_bias[2*a]   * expf(tw) / Wf;
  float bh = c_bias[2*a+1] * expf(th) / Hf;
  float netw = Wf * 32.0f;
  float neth = Hf * 32.0f;
  float imh = im_info[0], imw = im_info[1];
  bool cond   = (netw / imw) < (neth / imh);
  float new_w = cond ? netw : (imw * neth / imh);
  float new_h = cond ? (imh * netw / imw) : neth;
  bx = (bx - (netw - new_w) * 0.5f / netw) / (new_w / netw);
  by = (by - (neth - new_h) * 0.5f / neth) / (new_h / neth);
  bw = bw * (netw / new_w);
  bh = bh * (neth / new_h);
  float X  = bx * imw, Y = by * imh, Wd = bw * imw, Hd = bh * imh;

  float* ob = out + (size_t)NB * NBOX * PROBC + ((size_t)b * NBOX + n) * 4;
  ob[0] = X; ob[1] = Y; ob[2] = Wd; ob[3] = Hd;

  scores[t] = (obj < PRE_TH) ? 0.f : obj;
}

// ------------------------------------------------------------------ sort ----
// Wave-synchronous bitonic: 16 waves x 256-element spans; intra-span stages
// (j<=128) run barrier-free, only cross-wave steps (j>=256) use __syncthreads.
__global__ __launch_bounds__(1024) void k_sort(const float* __restrict__ scores,
                                               const float* __restrict__ out,   // bbox region read
                                               float* __restrict__ sScore,
                                               int* __restrict__ sIdx,
                                               float4* __restrict__ sBox,
                                               unsigned long long* __restrict__ posm,
                                               int* __restrict__ cnt) {
  int b    = blockIdx.x;
  int tid  = threadIdx.x;
  int lane = tid & 63;
  int wv   = tid >> 6;                              // 0..15, span [wv*256, wv*256+256)
  __shared__ unsigned long long key[NPAD];

  if (tid < SWRD) cnt[b * SWRD + tid] = 0;

  for (int i = tid; i < NPAD; i += 1024) {
    unsigned long long k = 0ULL;
    if (i < NBOX) {
      float s = scores[b * NBOX + i];
      unsigned int bits = __float_as_uint(s);       // s >= 0 -> monotone bits
      k = ((unsigned long long)bits << 32) | (unsigned long long)(0xFFFFFFFFu - (unsigned)i);
    }
    key[i] = k;
  }
  __syncthreads();

  // Phase A: k=2..256 — fully wave-local, no barriers
  for (int k = 2; k <= 256; k <<= 1) {
    for (int j = k >> 1; j > 0; j >>= 1) {
#pragma unroll
      for (int qq = 0; qq < 2; ++qq) {
        int q  = lane + (qq << 6);                  // 0..127: pair index in span
        int li = ((q & ~(j - 1)) << 1) | (q & (j - 1));
        int i  = (wv << 8) + li;
        int ix = i | j;
        bool desc = ((i & k) == 0);
        unsigned long long a = key[i], c = key[ix];
        bool sw = desc ? (a < c) : (a > c);
        if (sw) { key[i] = c; key[ix] = a; }
      }
      asm volatile("" ::: "memory");                // pin DS order; wave-sync
    }
  }
  __syncthreads();

  // Phase B: k=512..4096 — cross-wave steps barriered, local tail barrier-free
  for (int k = 512; k <= NPAD; k <<= 1) {
    for (int j = k >> 1; j >= 256; j >>= 1) {
#pragma unroll
      for (int qq = 0; qq < 2; ++qq) {
        int q  = tid + (qq << 10);                  // 0..2047: global pair index
        int i  = ((q & ~(j - 1)) << 1) | (q & (j - 1));
        int ix = i | j;
        bool desc = ((i & k) == 0);
        unsigned long long a = key[i], c = key[ix];
        bool sw = desc ? (a < c) : (a > c);
        if (sw) { key[i] = c; key[ix] = a; }
      }
      __syncthreads();
    }
    {
      bool desc = (((wv << 8) & k) == 0);           // uniform per span for k>=512
      for (int j = 128; j > 0; j >>= 1) {
#pragma unroll
        for (int qq = 0; qq < 2; ++qq) {
          int q  = lane + (qq << 6);
          int li = ((q & ~(j - 1)) << 1) | (q & (j - 1));
          int i  = (wv << 8) + li;
          int ix = i | j;
          unsigned long long a = key[i], c = key[ix];
          bool sw = desc ? (a < c) : (a > c);
          if (sw) { key[i] = c; key[ix] = a; }
        }
        asm volatile("" ::: "memory");
      }
      __syncthreads();
    }
  }

  const float4* outBox = (const float4*)(out + (size_t)NB * NBOX * PROBC);
  for (int i = tid; i < NPAD; i += 1024) {
    unsigned long long k = key[i];
    float s = __uint_as_float((unsigned)(k >> 32));
    bool pos = (k >> 32) != 0ULL;                   // s > 0
    unsigned long long bal = __ballot(pos);
    if ((tid & 63) == 0) posm[b * NWRD + (i >> 6)] = bal;
    sScore[b * NPAD + i] = s;
    int oi = (int)(0xFFFFFFFFu - (unsigned)(k & 0xFFFFFFFFu));
    sIdx[b * NPAD + i] = oi;
    float4 bx = make_float4(0.f, 0.f, 0.f, 0.f);
    if (oi >= 0 && oi < NBOX) bx = outBox[(size_t)b * NBOX + oi];
    sBox[b * NPAD + i] = bx;
  }
}

// ---------------------------------------------------------------- supmat ----
// 128 rows per wave (2 per lane): each LDS broadcast feeds two IoUs.
// Division-free predicate: inter*(1+TH) > TH*(areai+eps) + TH*aj
__global__ __launch_bounds__(64) void k_supmat(const float4* __restrict__ sBox,
                                               unsigned long long* __restrict__ diag,
                                               ulonglong2* __restrict__ entries,
                                               int* __restrict__ cnt) {
  int colg = blockIdx.x;                            // 0..52
  int rg   = blockIdx.y;                            // 0..26, rows [rg*128, rg*128+128)
  if (colg < 2 * rg) return;                        // strictly-lower blocks never read
  int b = blockIdx.z;
  int l = threadIdx.x;                              // 0..63

  __shared__ float4 corn[64];                       // col corners x1,y1,x2,y2
  __shared__ float  carTH[64];                      // TH * col area

  float4 cb = sBox[(size_t)b * NPAD + colg * 64 + l];
  float c1 = cb.x - cb.z * 0.5f;
  float d1 = cb.y - cb.w * 0.5f;
  float c2 = cb.x + cb.z * 0.5f;
  float d2 = cb.y + cb.w * 0.5f;
  corn[l]  = make_float4(c1, d1, c2, d2);
  carTH[l] = NMS_TH * ((c2 - c1) * (d2 - d1));
  __syncthreads();

  int row0 = rg * 128 + l;                          // lies in col-group 2*rg
  int row1 = row0 + 64;                             // lies in col-group 2*rg+1
  float4 r0 = sBox[(size_t)b * NPAD + row0];
  float4 r1 = sBox[(size_t)b * NPAD + row1];        // rg=26: padded zero boxes, safe
  float a0x1 = r0.x - r0.z * 0.5f, a0y1 = r0.y - r0.w * 0.5f;
  float a0x2 = r0.x + r0.z * 0.5f, a0y2 = r0.y + r0.w * 0.5f;
  float a1x1 = r1.x - r1.z * 0.5f, a1y1 = r1.y - r1.w * 0.5f;
  float a1x2 = r1.x + r1.z * 0.5f, a1y2 = r1.y + r1.w * 0.5f;
  float rc0 = NMS_TH * ((a0x2 - a0x1) * (a0y2 - a0y1) + 1e-12f);
  float rc1 = NMS_TH * ((a1x2 - a1x1) * (a1y2 - a1y1) + 1e-12f);
  const float OPT = 1.0f + NMS_TH;

  unsigned long long bits0 = 0ULL, bits1 = 0ULL;
#pragma unroll 4
  for (int t2 = 0; t2 < 64; ++t2) {
    float4 cc = corn[t2];                           // broadcast — conflict-free
    float ct  = carTH[t2];
    float iw0 = fmaxf(fminf(a0x2, cc.z) - fmaxf(a0x1, cc.x), 0.0f);
    float ih0 = fmaxf(fminf(a0y2, cc.w) - fmaxf(a0y1, cc.y), 0.0f);
    float iw1 = fmaxf(fminf(a1x2, cc.z) - fmaxf(a1x1, cc.x), 0.0f);
    float ih1 = fmaxf(fminf(a1y2, cc.w) - fmaxf(a1y1, cc.y), 0.0f);
    bool s0 = (iw0 * ih0) * OPT > rc0 + ct;
    bool s1 = (iw1 * ih1) * OPT > rc1 + ct;
    bits0 |= s0 ? (1ULL << t2) : 0ULL;
    bits1 |= s1 ? (1ULL << t2) : 0ULL;
  }

  unsigned long long selfmask = (l < 63) ? ((~0ULL) << (l + 1)) : 0ULL;
  if (colg == 2 * rg) {
    diag[((size_t)b * SWRD + colg) * 64 + l] = bits0 & selfmask;
  } else if (colg == 2 * rg + 1) {
    if (bits0 && row0 < NROW) {
      int p = atomicAdd(&cnt[b * SWRD + colg], 1);  // order-free: OR is commutative
      if (p < 64 * colg)
        entries[(size_t)b * ETOT + SEGB(colg) + p] =
            ulonglong2{(unsigned long long)row0, bits0};
    }
    diag[((size_t)b * SWRD + colg) * 64 + l] = bits1 & selfmask;
  } else {
    if (bits0 && row0 < NROW) {
      int p = atomicAdd(&cnt[b * SWRD + colg], 1);
      if (p < 64 * colg)
        entries[(size_t)b * ETOT + SEGB(colg) + p] =
            ulonglong2{(unsigned long long)row0, bits0};
    }
    if (bits1 && row1 < NROW) {
      int p = atomicAdd(&cnt[b * SWRD + colg], 1);
      if (p < 64 * colg)
        entries[(size_t)b * ETOT + SEGB(colg) + p] =
            ulonglong2{(unsigned long long)row1, bits1};
    }
  }
}

// ------------------------------------------------------------------ scan ----
// Single-wave greedy NMS (R15 design) + defensive hardening:
//  - (unsigned)row < NROW guard before any LDS index derived from entries
//  - per-chunk entry count clamped to segment capacity c*64
//  - one __syncthreads() after init (single-wave block: ~free) pinning all
//    init LDS/global traffic before the serial loop
//  - compiler memory-order pin at loop end (HW same-wave DS order is in-order)
__global__ __launch_bounds__(64) void k_scan(const unsigned long long* __restrict__ diag,
                                             const ulonglong2* __restrict__ entries,
                                             const int* __restrict__ cnt,
                                             const unsigned long long* __restrict__ posm,
                                             const float* __restrict__ sScore,
                                             const int* __restrict__ sIdx,
                                             float* __restrict__ out) {
  int b    = blockIdx.x;
  int lane = threadIdx.x;                           // 0..63

  __shared__ unsigned long long diagS[SWRD * 64];   // 27 KB
  __shared__ unsigned long long remv[SWRD];
  __shared__ int offs[SWRD + 1];

  const ulonglong2* segB = entries + (size_t)b * ETOT;

  if (lane < SWRD) remv[lane] = ~posm[b * NWRD + lane];  // bit set = suppressed
  for (int i = lane; i < SWRD * 64; i += 64)             // independent, pipelined
    diagS[i] = diag[(size_t)b * SWRD * 64 + i];

  {                                                 // prefix-sum the 53 counts
    int v = (lane < SWRD) ? cnt[b * SWRD + lane] : 0;
    if (v < 0) v = 0;
    int s = v;
#pragma unroll
    for (int d = 1; d < 64; d <<= 1) {
      int o = __shfl_up(s, d);
      if (lane >= d) s += o;
    }
    if (lane < SWRD) offs[lane + 1] = s;
    if (lane == 0)  offs[0] = 0;
  }
  __syncthreads();                                  // single wave: ~free

  for (int c = 0; c < SWRD; ++c) {
    int ne = offs[c + 1] - offs[c];
    int cap = c << 6;
    if (ne > cap) ne = cap;                         // defensive clamp
    unsigned long long acc = 0ULL;
    for (int g = lane; g < ne; g += 64) {           // coalesced, state-independent
      ulonglong2 e = segB[SEGB(c) + g];
      unsigned int row = (unsigned int)e.x;
      if (row < (unsigned)NROW &&
          !((remv[row >> 6] >> (row & 63)) & 1ULL)) acc |= e.y;
    }
#pragma unroll
    for (int off = 32; off >= 1; off >>= 1) acc |= __shfl_xor(acc, off);

    unsigned long long cur = remv[c] | acc;         // uniform across lanes
    unsigned long long dg  = diagS[(c << 6) + lane];

    // pruned greedy leader walk (all quantities wave-uniform)
    unsigned long long m = __ballot(dg != 0ULL) & ~cur;
    while (m) {
      int k = __ffsll((long long)m) - 1;
      cur |= rl64(dg, k);
      m &= m - 1;                                   // clear visited leader
      m &= ~cur;                                    // drop newly-suppressed lanes
    }
    if (lane == 0) remv[c] = cur;
    asm volatile("" ::: "memory");                  // pin LDS order across iters
  }

  // kept set == bits still clear
  for (int p = lane; p < NBOX; p += 64) {
    if (!((remv[p >> 6] >> (p & 63)) & 1ULL)) {
      int oi  = sIdx[b * NPAD + p];
      float s = sScore[b * NPAD + p];
      if (oi >= 0 && oi < NBOX)
        out[((size_t)b * NBOX + oi) * PROBC + NCLS] = s;
    }
  }
}

// ---------------------------------------------------------------- launch ----
extern "C" void kernel_launch(void* const* d_in, const int* in_sizes, int n_in,
                              void* d_out, int out_size, void* d_ws, size_t ws_size,
                              hipStream_t stream) {
  const float* x  = (const float*)d_in[0];
  const float* im = (const float*)d_in[1];
  float* out = (float*)d_out;

  float* scores = (float*)d_ws;                                   // NB*NBOX
  float* sScore = scores + (size_t)NB * NBOX;                     // NB*NPAD
  int*   sIdx   = (int*)(sScore + (size_t)NB * NPAD);             // NB*NPAD
  float4* sBox  = (float4*)(sIdx + (size_t)NB * NPAD);            // NB*NPAD (16B-aligned)
  unsigned long long* posm = (unsigned long long*)(sBox + (size_t)NB * NPAD); // NB*NWRD
  unsigned long long* diag = posm + (size_t)NB * NWRD;            // NB*SWRD*64
  int* cnt = (int*)(diag + (size_t)NB * SWRD * 64);               // NB*SWRD
  // pad cnt region to 16B alignment for ulonglong2 entries
  ulonglong2* entries = (ulonglong2*)((char*)cnt + (((size_t)NB * SWRD * 4 + 15) & ~(size_t)15)); // NB*ETOT

  hipLaunchKernelGGL(k_decode, dim3((NB * NBOX + 255) / 256), dim3(256), 0, stream,
                     x, im, out, scores);
  hipLaunchKernelGGL(k_sort, dim3(NB), dim3(1024), 0, stream,
                     scores, out, sScore, sIdx, sBox, posm, cnt);
  hipLaunchKernelGGL(k_supmat, dim3(SWRD, RGRP, NB), dim3(64), 0, stream,
                     sBox, diag, entries, cnt);
  hipLaunchKernelGGL(k_scan, dim3(NB), dim3(64), 0, stream,
                     diag, entries, cnt, posm, sScore, sIdx, out);
}

// Round 17
// 192.443 us; speedup vs baseline: 1.3821x; 1.3821x over previous
//
#include <hip/hip_runtime.h>
#include <stdint.h>

#pragma clang fp contract(off)

#define NCLS   20
#define NA     5
#define NB     16
#define Hg     26
#define Wg     26
#define HWc    (Hg*Wg)            // 676
#define NBOX   (NA*HWc)           // 3380
#define NPAD   4096
#define NWRD   (NPAD/64)          // 64
#define NROW   3392               // 53*64, padded row count
#define SWRD   53                 // words covering 3380 boxes
#define RGRP   27                 // ceil(NROW/128): 128-row groups
#define PROBC  (NCLS+1)           // 21
#define PRE_TH 0.005f
#define NMS_TH 0.45f
#define ECHUNK 512                // LDS entries per ring slot (4 slots)
#define ETOT   88192              // 32*53*52: worst-case entries per batch
#define SEGB(c) (32*(c)*((c)-1))  // segment base for chunk c (capacity c*64)

__constant__ float c_bias[10] = {1.08f,1.19f,3.42f,4.41f,6.63f,11.38f,9.42f,5.11f,16.62f,10.52f};

__device__ __forceinline__ unsigned long long rl64(unsigned long long v, int k) {
  unsigned int lo = (unsigned int)__builtin_amdgcn_readlane((int)(unsigned int)v, k);
  unsigned int hi = (unsigned int)__builtin_amdgcn_readlane((int)(unsigned int)(v >> 32), k);
  return ((unsigned long long)hi << 32) | lo;
}

// ---------------------------------------------------------------- decode ----
__global__ __launch_bounds__(256) void k_decode(const float* __restrict__ x,
                                                const float* __restrict__ im_info,
                                                float* __restrict__ out,
                                                float* __restrict__ scores) {
  int t = blockIdx.x * 256 + threadIdx.x;
  if (t >= NB * NBOX) return;
  int b  = t / NBOX;
  int n  = t - b * NBOX;
  int a  = n / HWc;
  int hw = n - a * HWc;
  int h  = hw / Wg;
  int w  = hw - h * Wg;

  const float* xb = x + (size_t)b * 125 * HWc;
  float tx = xb[(2*a  ) * HWc + hw];
  float ty = xb[(2*a+1) * HWc + hw];
  float tw = xb[(10+2*a) * HWc + hw];
  float th = xb[(11+2*a) * HWc + hw];
  float to = xb[(20+a  ) * HWc + hw];

  float sx  = 1.0f / (1.0f + expf(-tx));
  float sy  = 1.0f / (1.0f + expf(-ty));
  float obj = 1.0f / (1.0f + expf(-to));

  float cf[NCLS];
  float mx = -3.402823e38f;
#pragma unroll
  for (int c = 0; c < NCLS; ++c) {
    cf[c] = xb[(25 + c*NA + a) * HWc + hw];
    mx = fmaxf(mx, cf[c]);
  }
  float sum = 0.f;
#pragma unroll
  for (int c = 0; c < NCLS; ++c) { cf[c] = expf(cf[c] - mx); sum += cf[c]; }

  float* op = out + ((size_t)b * NBOX + n) * PROBC;
#pragma unroll
  for (int c = 0; c < NCLS; ++c) op[c] = cf[c] / sum * obj;
  op[NCLS] = 0.f;   // obj channel; scan kernel writes kept scores later

  // box decode — replicate reference op order exactly
  float Wf = (float)Wg, Hf = (float)Hg;
  float bx = ((float)w + sx) / Wf;
  float by = ((float)h + sy) / Hf;
  float bw = c_bias[2*a]   * expf(tw) / Wf;
  float bh = c_bias[2*a+1] * expf(th) / Hf;
  float netw = Wf * 32.0f;
  float neth = Hf * 32.0f;
  float imh = im_info[0], imw = im_info[1];
  bool cond   = (netw / imw) < (neth / imh);
  float new_w = cond ? netw : (imw * neth / imh);
  float new_h = cond ? (imh * netw / imw) : neth;
  bx = (bx - (netw - new_w) * 0.5f / netw) / (new_w / netw);
  by = (by - (neth - new_h) * 0.5f / neth) / (new_h / neth);
  bw = bw * (netw / new_w);
  bh = bh * (neth / new_h);
  float X  = bx * imw, Y = by * imh, Wd = bw * imw, Hd = bh * imh;

  float* ob = out + (size_t)NB * NBOX * PROBC + ((size_t)b * NBOX + n) * 4;
  ob[0] = X; ob[1] = Y; ob[2] = Wd; ob[3] = Hd;

  scores[t] = (obj < PRE_TH) ? 0.f : obj;
}

// ------------------------------------------------------------------ sort ----
// Wave-synchronous bitonic: 16 waves x 256-element spans; intra-span stages
// (j<=128) run barrier-free, only cross-wave steps (j>=256) use __syncthreads.
__global__ __launch_bounds__(1024) void k_sort(const float* __restrict__ scores,
                                               const float* __restrict__ out,   // bbox region read
                                               float* __restrict__ sScore,
                                               int* __restrict__ sIdx,
                                               float4* __restrict__ sBox,
                                               unsigned long long* __restrict__ posm,
                                               int* __restrict__ cnt) {
  int b    = blockIdx.x;
  int tid  = threadIdx.x;
  int lane = tid & 63;
  int wv   = tid >> 6;                              // 0..15, span [wv*256, wv*256+256)
  __shared__ unsigned long long key[NPAD];

  if (tid < SWRD) cnt[b * SWRD + tid] = 0;

  for (int i = tid; i < NPAD; i += 1024) {
    unsigned long long k = 0ULL;
    if (i < NBOX) {
      float s = scores[b * NBOX + i];
      unsigned int bits = __float_as_uint(s);       // s >= 0 -> monotone bits
      k = ((unsigned long long)bits << 32) | (unsigned long long)(0xFFFFFFFFu - (unsigned)i);
    }
    key[i] = k;
  }
  __syncthreads();

  // Phase A: k=2..256 — fully wave-local, no barriers
  for (int k = 2; k <= 256; k <<= 1) {
    for (int j = k >> 1; j > 0; j >>= 1) {
#pragma unroll
      for (int qq = 0; qq < 2; ++qq) {
        int q  = lane + (qq << 6);                  // 0..127: pair index in span
        int li = ((q & ~(j - 1)) << 1) | (q & (j - 1));
        int i  = (wv << 8) + li;
        int ix = i | j;
        bool desc = ((i & k) == 0);
        unsigned long long a = key[i], c = key[ix];
        bool sw = desc ? (a < c) : (a > c);
        if (sw) { key[i] = c; key[ix] = a; }
      }
      asm volatile("" ::: "memory");                // pin DS order; wave-sync
    }
  }
  __syncthreads();

  // Phase B: k=512..4096 — cross-wave steps barriered, local tail barrier-free
  for (int k = 512; k <= NPAD; k <<= 1) {
    for (int j = k >> 1; j >= 256; j >>= 1) {
#pragma unroll
      for (int qq = 0; qq < 2; ++qq) {
        int q  = tid + (qq << 10);                  // 0..2047: global pair index
        int i  = ((q & ~(j - 1)) << 1) | (q & (j - 1));
        int ix = i | j;
        bool desc = ((i & k) == 0);
        unsigned long long a = key[i], c = key[ix];
        bool sw = desc ? (a < c) : (a > c);
        if (sw) { key[i] = c; key[ix] = a; }
      }
      __syncthreads();
    }
    {
      bool desc = (((wv << 8) & k) == 0);           // uniform per span for k>=512
      for (int j = 128; j > 0; j >>= 1) {
#pragma unroll
        for (int qq = 0; qq < 2; ++qq) {
          int q  = lane + (qq << 6);
          int li = ((q & ~(j - 1)) << 1) | (q & (j - 1));
          int i  = (wv << 8) + li;
          int ix = i | j;
          unsigned long long a = key[i], c = key[ix];
          bool sw = desc ? (a < c) : (a > c);
          if (sw) { key[i] = c; key[ix] = a; }
        }
        asm volatile("" ::: "memory");
      }
      __syncthreads();
    }
  }

  const float4* outBox = (const float4*)(out + (size_t)NB * NBOX * PROBC);
  for (int i = tid; i < NPAD; i += 1024) {
    unsigned long long k = key[i];
    float s = __uint_as_float((unsigned)(k >> 32));
    bool pos = (k >> 32) != 0ULL;                   // s > 0
    unsigned long long bal = __ballot(pos);
    if ((tid & 63) == 0) posm[b * NWRD + (i >> 6)] = bal;
    sScore[b * NPAD + i] = s;
    int oi = (int)(0xFFFFFFFFu - (unsigned)(k & 0xFFFFFFFFu));
    sIdx[b * NPAD + i] = oi;
    float4 bx = make_float4(0.f, 0.f, 0.f, 0.f);
    if (oi >= 0 && oi < NBOX) bx = outBox[(size_t)b * NBOX + oi];
    sBox[b * NPAD + i] = bx;
  }
}

// ---------------------------------------------------------------- supmat ----
// 128 rows per wave (2 per lane): each LDS broadcast feeds two IoUs.
// Division-free predicate: inter*(1+TH) > TH*(areai+eps) + TH*aj
__global__ __launch_bounds__(64) void k_supmat(const float4* __restrict__ sBox,
                                               unsigned long long* __restrict__ diag,
                                               ulonglong2* __restrict__ entries,
                                               int* __restrict__ cnt) {
  int colg = blockIdx.x;                            // 0..52
  int rg   = blockIdx.y;                            // 0..26, rows [rg*128, rg*128+128)
  if (colg < 2 * rg) return;                        // strictly-lower blocks never read
  int b = blockIdx.z;
  int l = threadIdx.x;                              // 0..63

  __shared__ float4 corn[64];                       // col corners x1,y1,x2,y2
  __shared__ float  carTH[64];                      // TH * col area

  float4 cb = sBox[(size_t)b * NPAD + colg * 64 + l];
  float c1 = cb.x - cb.z * 0.5f;
  float d1 = cb.y - cb.w * 0.5f;
  float c2 = cb.x + cb.z * 0.5f;
  float d2 = cb.y + cb.w * 0.5f;
  corn[l]  = make_float4(c1, d1, c2, d2);
  carTH[l] = NMS_TH * ((c2 - c1) * (d2 - d1));
  __syncthreads();

  int row0 = rg * 128 + l;                          // lies in col-group 2*rg
  int row1 = row0 + 64;                             // lies in col-group 2*rg+1
  float4 r0 = sBox[(size_t)b * NPAD + row0];
  float4 r1 = sBox[(size_t)b * NPAD + row1];        // rg=26: padded zero boxes, safe
  float a0x1 = r0.x - r0.z * 0.5f, a0y1 = r0.y - r0.w * 0.5f;
  float a0x2 = r0.x + r0.z * 0.5f, a0y2 = r0.y + r0.w * 0.5f;
  float a1x1 = r1.x - r1.z * 0.5f, a1y1 = r1.y - r1.w * 0.5f;
  float a1x2 = r1.x + r1.z * 0.5f, a1y2 = r1.y + r1.w * 0.5f;
  float rc0 = NMS_TH * ((a0x2 - a0x1) * (a0y2 - a0y1) + 1e-12f);
  float rc1 = NMS_TH * ((a1x2 - a1x1) * (a1y2 - a1y1) + 1e-12f);
  const float OPT = 1.0f + NMS_TH;

  unsigned long long bits0 = 0ULL, bits1 = 0ULL;
#pragma unroll 4
  for (int t2 = 0; t2 < 64; ++t2) {
    float4 cc = corn[t2];                           // broadcast — conflict-free
    float ct  = carTH[t2];
    float iw0 = fmaxf(fminf(a0x2, cc.z) - fmaxf(a0x1, cc.x), 0.0f);
    float ih0 = fmaxf(fminf(a0y2, cc.w) - fmaxf(a0y1, cc.y), 0.0f);
    float iw1 = fmaxf(fminf(a1x2, cc.z) - fmaxf(a1x1, cc.x), 0.0f);
    float ih1 = fmaxf(fminf(a1y2, cc.w) - fmaxf(a1y1, cc.y), 0.0f);
    bool s0 = (iw0 * ih0) * OPT > rc0 + ct;
    bool s1 = (iw1 * ih1) * OPT > rc1 + ct;
    bits0 |= s0 ? (1ULL << t2) : 0ULL;
    bits1 |= s1 ? (1ULL << t2) : 0ULL;
  }

  unsigned long long selfmask = (l < 63) ? ((~0ULL) << (l + 1)) : 0ULL;
  if (colg == 2 * rg) {
    diag[((size_t)b * SWRD + colg) * 64 + l] = bits0 & selfmask;
  } else if (colg == 2 * rg + 1) {
    if (bits0) {
      int p = atomicAdd(&cnt[b * SWRD + colg], 1);  // order-free: OR is commutative
      entries[(size_t)b * ETOT + SEGB(colg) + p] =
          ulonglong2{(unsigned long long)row0, bits0};
    }
    diag[((size_t)b * SWRD + colg) * 64 + l] = bits1 & selfmask;
  } else {
    if (bits0) {
      int p = atomicAdd(&cnt[b * SWRD + colg], 1);
      entries[(size_t)b * ETOT + SEGB(colg) + p] =
          ulonglong2{(unsigned long long)row0, bits0};
    }
    if (bits1) {
      int p = atomicAdd(&cnt[b * SWRD + colg], 1);
      entries[(size_t)b * ETOT + SEGB(colg) + p] =
          ulonglong2{(unsigned long long)row1, bits1};
    }
  }
}

// ------------------------------------------------------------------ scan ----
// R14 producer/consumer structure (proven 58 us), unrolled x2: iteration i,
// wave 0 resolves chunks 2i and 2i+1 sequentially from LDS (same-wave DS
// ordering makes remv[2i] visible to resolve(2i+1)), waves 1-7 prefetch
// chunks 2i+2, 2i+3 into a 4-slot SoA ring. 53 -> 27 barrier iterations.
// Global-read overflow path for chunks with > ECHUNK entries.
__global__ __launch_bounds__(512) void k_scan(const unsigned long long* __restrict__ diag,
                                              const ulonglong2* __restrict__ entries,
                                              const int* __restrict__ cnt,
                                              const unsigned long long* __restrict__ posm,
                                              const float* __restrict__ sScore,
                                              const int* __restrict__ sIdx,
                                              float* __restrict__ out) {
  int b    = blockIdx.x;
  int tid  = threadIdx.x;
  int lane = tid & 63;
  int wid  = tid >> 6;
  __shared__ unsigned long long diagS[SWRD * 64];   // 27 KB
  __shared__ unsigned long long bitsE[4][ECHUNK];   // 16 KB ring (SoA)
  __shared__ unsigned short     rowE[4][ECHUNK];    //  4 KB ring (SoA)
  __shared__ unsigned long long remv[SWRD];
  __shared__ int cntS[SWRD];

  const ulonglong2* segB = entries + (size_t)b * ETOT;

  if (tid < SWRD) {
    remv[tid] = ~posm[b * NWRD + tid];              // bit set = suppressed/invalid
    cntS[tid] = cnt[b * SWRD + tid];
  }
  for (int i = tid; i < SWRD * 64; i += 512)
    diagS[i] = diag[(size_t)b * SWRD * 64 + i];
  __syncthreads();

  // prologue: preload chunks 0,1 (chunk 0 is always empty)
  {
    int nn = cntS[1];
    if (nn > ECHUNK) nn = ECHUNK;
    const ulonglong2* sp = segB + SEGB(1);
    for (int g = tid; g < nn; g += 512) {
      ulonglong2 e = sp[g];
      bitsE[1][g] = e.y;
      rowE[1][g]  = (unsigned short)e.x;
    }
  }
  __syncthreads();

  for (int i = 0; i < RGRP; ++i) {                  // 27 iterations, 2 chunks each
    int c0 = 2 * i;
    if (wid > 0) {
      // waves 1-7: prefetch chunks c0+2, c0+3 into ring slots (disjoint from
      // the two slots wave 0 is consuming this iteration)
#pragma unroll
      for (int d = 2; d <= 3; ++d) {
        int cc = c0 + d;
        if (cc < SWRD) {
          int nn = cntS[cc];
          if (nn > ECHUNK) nn = ECHUNK;
          const ulonglong2* sp = segB + SEGB(cc);
          int slot = cc & 3;
          for (int g = tid - 64; g < nn; g += 448) {
            ulonglong2 e = sp[g];
            bitsE[slot][g] = e.y;
            rowE[slot][g]  = (unsigned short)e.x;
          }
        }
      }
    } else {
      // wave 0: resolve chunks c0 and c0+1 sequentially
#pragma unroll
      for (int d = 0; d <= 1; ++d) {
        int c = c0 + d;
        if (c >= SWRD) break;
        int nc = cntS[c];
        int nl = nc > ECHUNK ? ECHUNK : nc;
        int slot = c & 3;
        unsigned long long acc = 0ULL;
        for (int g = lane; g < nl; g += 64) {
          int row = rowE[slot][g];
          if (!((remv[row >> 6] >> (row & 63)) & 1ULL)) acc |= bitsE[slot][g];
        }
        for (int g = ECHUNK + lane; g < nc; g += 64) {   // rare overflow path
          ulonglong2 e = segB[SEGB(c) + g];
          int row = (int)e.x;
          if (!((remv[row >> 6] >> (row & 63)) & 1ULL)) acc |= e.y;
        }
#pragma unroll
        for (int off = 32; off >= 1; off >>= 1) acc |= __shfl_xor(acc, off);

        unsigned long long cur = remv[c] | acc;        // uniform across lanes
        unsigned long long dg  = diagS[(c << 6) + lane];

        // pruned greedy leader walk (all quantities wave-uniform)
        unsigned long long m = __ballot(dg != 0ULL) & ~cur;
        while (m) {
          int k = __ffsll((long long)m) - 1;
          cur |= rl64(dg, k);
          m &= m - 1;                               // clear visited leader
          m &= ~cur;                                // drop newly-suppressed lanes
        }
        if (lane == 0) remv[c] = cur;
      }
    }
    __syncthreads();
  }

  // kept set == bits still clear
  for (int p = tid; p < NBOX; p += 512) {
    if (!((remv[p >> 6] >> (p & 63)) & 1ULL)) {
      int oi  = sIdx[b * NPAD + p];
      float s = sScore[b * NPAD + p];
      out[((size_t)b * NBOX + oi) * PROBC + NCLS] = s;
    }
  }
}

// ---------------------------------------------------------------- launch ----
extern "C" void kernel_launch(void* const* d_in, const int* in_sizes, int n_in,
                              void* d_out, int out_size, void* d_ws, size_t ws_size,
                              hipStream_t stream) {
  const float* x  = (const float*)d_in[0];
  const float* im = (const float*)d_in[1];
  float* out = (float*)d_out;

  float* scores = (float*)d_ws;                                   // NB*NBOX
  float* sScore = scores + (size_t)NB * NBOX;                     // NB*NPAD
  int*   sIdx   = (int*)(sScore + (size_t)NB * NPAD);             // NB*NPAD
  float4* sBox  = (float4*)(sIdx + (size_t)NB * NPAD);            // NB*NPAD (16B-aligned)
  unsigned long long* posm = (unsigned long long*)(sBox + (size_t)NB * NPAD); // NB*NWRD
  unsigned long long* diag = posm + (size_t)NB * NWRD;            // NB*SWRD*64
  int* cnt = (int*)(diag + (size_t)NB * SWRD * 64);               // NB*SWRD
  // pad cnt region to 16B alignment for ulonglong2 entries
  ulonglong2* entries = (ulonglong2*)((char*)cnt + (((size_t)NB * SWRD * 4 + 15) & ~(size_t)15)); // NB*ETOT

  hipLaunchKernelGGL(k_decode, dim3((NB * NBOX + 255) / 256), dim3(256), 0, stream,
                     x, im, out, scores);
  hipLaunchKernelGGL(k_sort, dim3(NB), dim3(1024), 0, stream,
                     scores, out, sScore, sIdx, sBox, posm, cnt);
  hipLaunchKernelGGL(k_supmat, dim3(SWRD, RGRP, NB), dim3(64), 0, stream,
                     sBox, diag, entries, cnt);
  hipLaunchKernelGGL(k_scan, dim3(NB), dim3(512), 0, stream,
                     diag, entries, cnt, posm, sScore, sIdx, out);
}